// Round 7
// baseline (1555864.648 us; speedup 1.0000x reference)
//
#include <hip/hip_runtime.h>

// CRF forward chain on MI355X — linearized: u' = (1/g) diag(exp(h_s)) E u.
// R13: XCD-LOCAL SYNC. R12 showed the per-step stall is the sc0sc1 (L3)
// round-trip itself, not hideable by pipelining (and 4-phase unroll blew I$).
// Fix: group = 16 blocks sharing blockIdx%8 (the empirical XCD round-robin),
// verified at runtime via s_getreg(HW_REG_XCC_ID) published through ws. If
// uniform: u-chain stores/loads use sc0 only -> coherence point is the shared
// per-XCD L2 (~200cyc) instead of L3 (~900cyc). Else: sc0sc1 fallback
// (correct, R11-like). Bounded-spin escalation (16K tries -> sc0sc1 loads)
// removes deadlock risk even if same-XCD sc0 visibility failed.
// Structure: R11's 2-chain cadence (I$-safe body), drain-free s_barrier
// (lgkmcnt only), poll AFTER GEMV (data stored >=1 phase ago), all 8 waves
// load full u (8x dwordx4) -> gmax without cross-wave reduce; each wave
// packs its 1/8 slice. One barrier per phase, 2 phases per T.
// NCH=32, CH_LEN=256, BURN=24, TCYC=280, 560 phases. 256 blocks = 1/CU.
//
// ws floats: u_bufs[32][2][2048] @0, usave[32][2048] @131072f,
// ufin[32][2048] @196608f, cbuf[32] @262144f ;
// posts int[2048] @byte 1048704 ; xcdbuf int[256] @byte 1056896.

#define TSZ   2048
#define NCH   32
#define NW    8
#define CH_LEN 256
#define BURN  24
#define TCYC  (CH_LEN + BURN)
#define START_I 0
#define END_I   1

typedef float v4f __attribute__((ext_vector_type(4)));
typedef _Float16 h2f __attribute__((ext_vector_type(2)));

__device__ __forceinline__ h2f pk16(float a, float b) {
    return __builtin_bit_cast(h2f, __builtin_amdgcn_cvt_pkrtz(a, b));
}
__device__ __forceinline__ void st_coh(float* p, float v) {
    asm volatile("global_store_dword %0, %1, off sc0 sc1"
                 :: "v"(p), "v"(v) : "memory");
}
__device__ __forceinline__ void st_coh_i(int* p, int v) {
    asm volatile("global_store_dword %0, %1, off sc0 sc1"
                 :: "v"(p), "v"(v) : "memory");
}
__device__ __forceinline__ int ld_coh_i(const int* p) {
    int r;
    asm volatile("global_load_dword %0, %1, off sc0 sc1\n\ts_waitcnt vmcnt(0)"
                 : "=&v"(r) : "v"(p) : "memory");
    return r;
}
__device__ __forceinline__ float ld_coh1(const float* p) {
    float r;
    asm volatile("global_load_dword %0, %1, off sc0 sc1\n\ts_waitcnt vmcnt(0)"
                 : "=&v"(r) : "v"(p) : "memory");
    return r;
}
__device__ __forceinline__ v4f ld_coh4(const float* p) {
    v4f r;
    asm volatile("global_load_dwordx4 %0, %1, off sc0 sc1\n\ts_waitcnt vmcnt(0)"
                 : "=&v"(r) : "v"(p) : "memory");
    return r;
}

// 8x dwordx4 poll load, flag-parameterized
#define POLL8(F)                                                              \
    asm volatile(                                                             \
        "global_load_dwordx4 %0, %8, off " F "\n\t"                           \
        "global_load_dwordx4 %1, %8, off offset:1024 " F "\n\t"               \
        "global_load_dwordx4 %2, %8, off offset:2048 " F "\n\t"               \
        "global_load_dwordx4 %3, %8, off offset:3072 " F "\n\t"               \
        "global_load_dwordx4 %4, %9, off " F "\n\t"                           \
        "global_load_dwordx4 %5, %9, off offset:1024 " F "\n\t"               \
        "global_load_dwordx4 %6, %9, off offset:2048 " F "\n\t"               \
        "global_load_dwordx4 %7, %9, off offset:3072 " F "\n\t"               \
        "s_waitcnt vmcnt(0)"                                                  \
        : "=&v"(u0), "=&v"(u1), "=&v"(u2), "=&v"(u3),                         \
          "=&v"(u4), "=&v"(u5), "=&v"(u6), "=&v"(u7)                          \
        : "v"(pa), "v"(pb)                                                    \
        : "memory")

__global__ __launch_bounds__(512, 1)
void crf_chain(const float* __restrict__ h, const float* __restrict__ tr,
               float* __restrict__ out, float* __restrict__ ws)
{
    const int tid  = threadIdx.x;
    const int lane = tid & 63;
    const int wv   = tid >> 6;          // 0..7
    const int blk  = blockIdx.x;
    // group: 16 blocks sharing blk%8 (same XCD under round-robin) and
    // (blk>>3)&1 parity. g = 0..15; b = 0..15.
    const int g    = (blk & 7) * 2 + ((blk >> 3) & 1);
    const int b    = blk >> 4;
    const int ca   = g;                 // chain X chunk 0..15
    const int cb   = g + 16;            // chain Y chunk 16..31
    const int row_base = b * 128 + wv * 16;

    float* u_bufs = ws;                               // [32][2][2048]
    float* usave  = ws + NCH * 2 * TSZ;               // [32][2048]
    float* ufin   = usave + NCH * TSZ;                // [32][2048]
    float* cbuf   = ufin + NCH * TSZ;                 // [32]
    int*   posts  = (int*)((char*)ws + 1048704);      // [2048]
    int*   xcdbuf = (int*)((char*)ws + 1056896);      // [256]

    __shared__ unsigned long long els64[32][512];     // 4 LDS E-rows/wave, 128KB
    __shared__ unsigned long long uh_sh[2][512];      // packed u per chain, 8KB

    // ---- publish XCD id EARLY (overlaps E setup on all blocks)
    int myxcd;
    asm volatile("s_getreg_b32 %0, hwreg(HW_REG_XCC_ID)" : "=s"(myxcd));
    if (tid == 0) st_coh_i(&xcdbuf[blk], myxcd + 1);   // poison 0xAA.. < 0

    // ---- one-time: register E fragment, 12 rows/wave.
    h2f e2r[12][16];
    #pragma unroll
    for (int r = 0; r < 12; ++r) {
        const float* trow = tr + (size_t)(row_base + r) * TSZ + 4 * lane;
        #pragma unroll
        for (int k = 0; k < 8; ++k) {
            float4 t4 = *(const float4*)(trow + 256 * k);
            e2r[r][2 * k]     = pk16(__expf(t4.x), __expf(t4.y));
            e2r[r][2 * k + 1] = pk16(__expf(t4.z), __expf(t4.w));
        }
    }
    // ---- one-time: LDS E rows 12..15 per wave.
    #pragma unroll
    for (int rr = 0; rr < 4; ++rr) {
        const float* trow = tr + (size_t)(row_base + 12 + rr) * TSZ + 4 * lane;
        #pragma unroll
        for (int k = 0; k < 8; ++k) {
            float4 t4 = *(const float4*)(trow + 256 * k);
            unsigned lo = __builtin_bit_cast(unsigned, pk16(__expf(t4.x), __expf(t4.y)));
            unsigned hi = __builtin_bit_cast(unsigned, pk16(__expf(t4.z), __expf(t4.w)));
            els64[wv * 4 + rr][lane + 64 * k] =
                ((unsigned long long)hi << 32) | (unsigned long long)lo;
        }
    }

    // ---- detect group-XCD uniformity (ground truth, per-launch)
    bool fast;
    {
        const int base = (g >> 1) + 8 * (g & 1);       // blkOf(j) = base + 16j
        int v = myxcd + 1;
        if (lane < 16) {
            const int* p = &xcdbuf[base + 16 * lane];
            do { v = ld_coh_i(p); } while (v <= 0);
        }
        fast = __all(v == myxcd + 1);
    }

    // fast/slow u-chain store
    auto ST_U = [&](float* p, float v) {
        if (fast) asm volatile("global_store_dword %0, %1, off sc0"
                               :: "v"(p), "v"(v) : "memory");
        else      asm volatile("global_store_dword %0, %1, off sc0 sc1"
                               :: "v"(p), "v"(v) : "memory");
    };

    const int q    = ((lane & 1) << 2) | (lane & 2) | ((lane >> 2) & 1);
    const int grow = row_base + q;          // rows grow, grow+8 for lane<8

    // chain schedules
    const int skX = ca * CH_LEN, seX = skX + CH_LEN;
    const int s0X = (ca == 0) ? 0 : (skX - BURN);
    const int TX  = (ca == 0) ? CH_LEN : TCYC;
    const int skY = cb * CH_LEN, seY = skY + CH_LEN;
    const int s0Y = skY - BURN;

    float* ubX = u_bufs + ca * 2 * TSZ;
    float* ubY = u_bufs + cb * 2 * TSZ;

    // ---- init: u^0 parity 0, POSITIVE tag
    if (tid < 128) {
        int row = b * 128 + tid;
        ST_U(&ubX[row], (ca == 0) ? ((row == START_I) ? 1.0f : 0.0f) : 1.0f);
        ST_U(&ubY[row], 1.0f);
    }

    float ChatX = 0.0f, ChatY = 0.0f;

    // ---- poll full u (8 loads/wave), gmax in-wave, pack own 1/8 slice
    auto POLL_PACK = [&](const float* ubase, int par, int in_neg, int cslot,
                         bool kept, float& ch) {
        const float* pa = ubase + par * TSZ + 4 * lane;   // k=0..3
        const float* pb = pa + 1024;                      // k=4..7
        v4f u0, u1, u2, u3, u4, u5, u6, u7;
        int tries = 0;
        for (;;) {
            if (fast && tries < 16384) POLL8("sc0");
            else                       POLL8("sc0 sc1");
            bool fresh;
            if (in_neg) {
                int a = __float_as_int(u0.x) & __float_as_int(u0.y) & __float_as_int(u0.z) & __float_as_int(u0.w);
                a &= __float_as_int(u1.x) & __float_as_int(u1.y) & __float_as_int(u1.z) & __float_as_int(u1.w);
                a &= __float_as_int(u2.x) & __float_as_int(u2.y) & __float_as_int(u2.z) & __float_as_int(u2.w);
                a &= __float_as_int(u3.x) & __float_as_int(u3.y) & __float_as_int(u3.z) & __float_as_int(u3.w);
                a &= __float_as_int(u4.x) & __float_as_int(u4.y) & __float_as_int(u4.z) & __float_as_int(u4.w);
                a &= __float_as_int(u5.x) & __float_as_int(u5.y) & __float_as_int(u5.z) & __float_as_int(u5.w);
                a &= __float_as_int(u6.x) & __float_as_int(u6.y) & __float_as_int(u6.z) & __float_as_int(u6.w);
                a &= __float_as_int(u7.x) & __float_as_int(u7.y) & __float_as_int(u7.z) & __float_as_int(u7.w);
                fresh = (a < 0);
            } else {
                int o = __float_as_int(u0.x) | __float_as_int(u0.y) | __float_as_int(u0.z) | __float_as_int(u0.w);
                o |= __float_as_int(u1.x) | __float_as_int(u1.y) | __float_as_int(u1.z) | __float_as_int(u1.w);
                o |= __float_as_int(u2.x) | __float_as_int(u2.y) | __float_as_int(u2.z) | __float_as_int(u2.w);
                o |= __float_as_int(u3.x) | __float_as_int(u3.y) | __float_as_int(u3.z) | __float_as_int(u3.w);
                o |= __float_as_int(u4.x) | __float_as_int(u4.y) | __float_as_int(u4.z) | __float_as_int(u4.w);
                o |= __float_as_int(u5.x) | __float_as_int(u5.y) | __float_as_int(u5.z) | __float_as_int(u5.w);
                o |= __float_as_int(u6.x) | __float_as_int(u6.y) | __float_as_int(u6.z) | __float_as_int(u6.w);
                o |= __float_as_int(u7.x) | __float_as_int(u7.y) | __float_as_int(u7.z) | __float_as_int(u7.w);
                fresh = (o >= 0);
            }
            if (__all(fresh)) break;
            ++tries;
        }
        float m;
        m =          fmaxf(fmaxf(fabsf(u0.x), fabsf(u0.y)), fmaxf(fabsf(u0.z), fabsf(u0.w)));
        m = fmaxf(m, fmaxf(fmaxf(fabsf(u1.x), fabsf(u1.y)), fmaxf(fabsf(u1.z), fabsf(u1.w))));
        m = fmaxf(m, fmaxf(fmaxf(fabsf(u2.x), fabsf(u2.y)), fmaxf(fabsf(u2.z), fabsf(u2.w))));
        m = fmaxf(m, fmaxf(fmaxf(fabsf(u3.x), fabsf(u3.y)), fmaxf(fabsf(u3.z), fabsf(u3.w))));
        m = fmaxf(m, fmaxf(fmaxf(fabsf(u4.x), fabsf(u4.y)), fmaxf(fabsf(u4.z), fabsf(u4.w))));
        m = fmaxf(m, fmaxf(fmaxf(fabsf(u5.x), fabsf(u5.y)), fmaxf(fabsf(u5.z), fabsf(u5.w))));
        m = fmaxf(m, fmaxf(fmaxf(fabsf(u6.x), fabsf(u6.y)), fmaxf(fabsf(u6.z), fabsf(u6.w))));
        m = fmaxf(m, fmaxf(fmaxf(fabsf(u7.x), fabsf(u7.y)), fmaxf(fabsf(u7.z), fabsf(u7.w))));
        #pragma unroll
        for (int d = 1; d < 64; d <<= 1) m = fmaxf(m, __shfl_xor(m, d, 64));

        const float rn = (in_neg ? -1.0f : 1.0f) / m;
        v4f mine = (wv < 4) ? ((wv < 2) ? ((wv == 0) ? u0 : u1)
                                        : ((wv == 2) ? u2 : u3))
                            : ((wv < 6) ? ((wv == 4) ? u4 : u5)
                                        : ((wv == 6) ? u6 : u7));
        unsigned lo = __builtin_bit_cast(unsigned, pk16(mine.x * rn, mine.y * rn));
        unsigned hi = __builtin_bit_cast(unsigned, pk16(mine.z * rn, mine.w * rn));
        uh_sh[cslot][lane + 64 * wv] =
            ((unsigned long long)hi << 32) | (unsigned long long)lo;
        if (kept) ch += __logf(m);
    };

    // ---- GEMV (16 rows/wave: 12 reg + 4 LDS)
    auto GEMV_COMPUTE = [&](const unsigned long long* uh_src, float& outA, float& outB) {
        h2f uh[16];
        #pragma unroll
        for (int k = 0; k < 8; ++k) {
            unsigned long long qw = uh_src[lane + 64 * k];
            uh[2 * k]     = __builtin_bit_cast(h2f, (unsigned)qw);
            uh[2 * k + 1] = __builtin_bit_cast(h2f, (unsigned)(qw >> 32));
        }
        float acc[8];
        #pragma unroll
        for (int r = 0; r < 8; ++r) acc[r] = 0.0f;
        #pragma unroll
        for (int k = 0; k < 16; ++k) {
            #pragma unroll
            for (int r = 0; r < 8; ++r)
                acc[r] = __builtin_amdgcn_fdot2(e2r[r][k], uh[k], acc[r], false);
        }
        #pragma unroll
        for (int r = 0; r < 4; ++r) {
            float send = (lane & 1) ? acc[r] : acc[r + 4];
            float recv = __shfl_xor(send, 1, 64);
            float keep = (lane & 1) ? acc[r + 4] : acc[r];
            acc[r] = keep + recv;
        }
        #pragma unroll
        for (int r = 0; r < 2; ++r) {
            float send = (lane & 2) ? acc[r] : acc[r + 2];
            float recv = __shfl_xor(send, 2, 64);
            float keep = (lane & 2) ? acc[r + 2] : acc[r];
            acc[r] = keep + recv;
        }
        {
            float send = (lane & 4) ? acc[0] : acc[1];
            float recv = __shfl_xor(send, 4, 64);
            float keep = (lane & 4) ? acc[1] : acc[0];
            acc[0] = keep + recv;
        }
        acc[0] += __shfl_xor(acc[0], 8, 64);
        acc[0] += __shfl_xor(acc[0], 16, 64);
        acc[0] += __shfl_xor(acc[0], 32, 64);
        outA = acc[0];

        #pragma unroll
        for (int r = 0; r < 8; ++r) acc[r] = 0.0f;
        #pragma unroll
        for (int k = 0; k < 8; ++k) {
            unsigned long long q0 = els64[wv * 4 + 0][lane + 64 * k];
            unsigned long long q1 = els64[wv * 4 + 1][lane + 64 * k];
            unsigned long long q2 = els64[wv * 4 + 2][lane + 64 * k];
            unsigned long long q3 = els64[wv * 4 + 3][lane + 64 * k];
            #pragma unroll
            for (int r = 0; r < 4; ++r) {
                acc[r] = __builtin_amdgcn_fdot2(e2r[8 + r][2 * k],     uh[2 * k],     acc[r], false);
                acc[r] = __builtin_amdgcn_fdot2(e2r[8 + r][2 * k + 1], uh[2 * k + 1], acc[r], false);
            }
            acc[4] = __builtin_amdgcn_fdot2(__builtin_bit_cast(h2f, (unsigned)q0),         uh[2 * k],     acc[4], false);
            acc[4] = __builtin_amdgcn_fdot2(__builtin_bit_cast(h2f, (unsigned)(q0 >> 32)), uh[2 * k + 1], acc[4], false);
            acc[5] = __builtin_amdgcn_fdot2(__builtin_bit_cast(h2f, (unsigned)q1),         uh[2 * k],     acc[5], false);
            acc[5] = __builtin_amdgcn_fdot2(__builtin_bit_cast(h2f, (unsigned)(q1 >> 32)), uh[2 * k + 1], acc[5], false);
            acc[6] = __builtin_amdgcn_fdot2(__builtin_bit_cast(h2f, (unsigned)q2),         uh[2 * k],     acc[6], false);
            acc[6] = __builtin_amdgcn_fdot2(__builtin_bit_cast(h2f, (unsigned)(q2 >> 32)), uh[2 * k + 1], acc[6], false);
            acc[7] = __builtin_amdgcn_fdot2(__builtin_bit_cast(h2f, (unsigned)q3),         uh[2 * k],     acc[7], false);
            acc[7] = __builtin_amdgcn_fdot2(__builtin_bit_cast(h2f, (unsigned)(q3 >> 32)), uh[2 * k + 1], acc[7], false);
        }
        #pragma unroll
        for (int r = 0; r < 4; ++r) {
            float send = (lane & 1) ? acc[r] : acc[r + 4];
            float recv = __shfl_xor(send, 1, 64);
            float keep = (lane & 1) ? acc[r + 4] : acc[r];
            acc[r] = keep + recv;
        }
        #pragma unroll
        for (int r = 0; r < 2; ++r) {
            float send = (lane & 2) ? acc[r] : acc[r + 2];
            float recv = __shfl_xor(send, 2, 64);
            float keep = (lane & 2) ? acc[r + 2] : acc[r];
            acc[r] = keep + recv;
        }
        {
            float send = (lane & 4) ? acc[0] : acc[1];
            float recv = __shfl_xor(send, 4, 64);
            float keep = (lane & 4) ? acc[1] : acc[0];
            acc[0] = keep + recv;
        }
        acc[0] += __shfl_xor(acc[0], 8, 64);
        acc[0] += __shfl_xor(acc[0], 16, 64);
        acc[0] += __shfl_xor(acc[0], 32, 64);
        outB = acc[0];
    };

    // drain-free barrier: LDS consistency only; stores stay in flight.
    auto BAR = [&]() {
        __builtin_amdgcn_sched_barrier(0);
        asm volatile("s_waitcnt lgkmcnt(0)" ::: "memory");
        __builtin_amdgcn_s_barrier();
        __builtin_amdgcn_sched_barrier(0);
    };

    // ---- prologue: pack chain X u_0 into uh_sh[0]
    POLL_PACK(ubX, 0, 0, 0, (s0X + 1) > skX, ChatX);
    BAR();   // els64 + uh_sh[0] ready

    // ================= main loop: 2 phases per T ============================
    for (int T = 0; T < TCYC; ++T) {
        const int outp = (T + 1) & 1, outn = ((T + 1) >> 1) & 1;

        // ---- even phase: compute X@T; poll+pack Y u_T (stored last iter)
        {
            const int sX = s0X + T;
            const bool doX = (T < TX);
            float h0 = 0.0f, h1 = 0.0f;
            if (doX && lane < 8) {
                h0 = h[(size_t)sX * TSZ + grow];
                h1 = h[(size_t)sX * TSZ + grow + 8];
            }
            if (doX) {
                float rA, rB;
                GEMV_COMPUTE(&uh_sh[0][0], rA, rB);
                if (lane < 8) {
                    float utA = rA * __expf(h0);
                    float utB = rB * __expf(h1);
                    float* uo = ubX + outp * TSZ;
                    ST_U(&uo[grow],     outn ? -utA : utA);
                    ST_U(&uo[grow + 8], outn ? -utB : utB);
                    if (ca > 0 && sX + 1 == skX) {
                        st_coh(&usave[ca * TSZ + grow],     utA);
                        st_coh(&usave[ca * TSZ + grow + 8], utB);
                    }
                    if (sX + 1 == seX) {
                        st_coh(&ufin[ca * TSZ + grow],     utA);
                        st_coh(&ufin[ca * TSZ + grow + 8], utB);
                    }
                }
            }
            // poll Y's u_T (v=T): parity T&1, tag (T>>1)&1
            POLL_PACK(ubY, T & 1, (T >> 1) & 1, 1, (s0Y + T + 1) > skY, ChatY);
            BAR();
        }

        // ---- odd phase: compute Y@T; poll+pack X u_{T+1} (stored above)
        {
            const int sY = s0Y + T;
            float h0 = 0.0f, h1 = 0.0f;
            if (lane < 8) {
                h0 = h[(size_t)sY * TSZ + grow];
                h1 = h[(size_t)sY * TSZ + grow + 8];
            }
            {
                float rA, rB;
                GEMV_COMPUTE(&uh_sh[1][0], rA, rB);
                if (lane < 8) {
                    float utA = rA * __expf(h0);
                    float utB = rB * __expf(h1);
                    float* uo = ubY + outp * TSZ;
                    ST_U(&uo[grow],     outn ? -utA : utA);
                    ST_U(&uo[grow + 8], outn ? -utB : utB);
                    if (sY + 1 == skY) {
                        st_coh(&usave[cb * TSZ + grow],     utA);
                        st_coh(&usave[cb * TSZ + grow + 8], utB);
                    }
                    if (sY + 1 == seY) {
                        st_coh(&ufin[cb * TSZ + grow],     utA);
                        st_coh(&ufin[cb * TSZ + grow + 8], utB);
                    }
                }
            }
            // poll X's u_{T+1} (v=T+1) if X still running
            const int v = T + 1;
            if (v < TX)
                POLL_PACK(ubX, v & 1, (v >> 1) & 1, 0, (s0X + v + 1) > skX, ChatX);
            BAR();
        }
    }

    // ---- completion: store Chats, ack all stores, per-wave post
    if (b == 0 && wv == 0 && lane == 0) {
        st_coh(&cbuf[ca], ChatX);
        st_coh(&cbuf[cb], ChatY);
    }
    asm volatile("s_waitcnt vmcnt(0)" ::: "memory");
    if (lane == 0)
        __hip_atomic_store(&posts[blk * NW + wv], 1,
                           __ATOMIC_RELAXED, __HIP_MEMORY_SCOPE_AGENT);

    // ---- finisher: blk 0 (g=0,b=0) wave 0 stitches 32 chunks
    if (blk == 0 && wv == 0) {
        int ok;
        do {
            __builtin_amdgcn_s_sleep(1);
            ok = 1;
            #pragma unroll
            for (int i = 0; i < 32; ++i) {     // 256 blocks x 8 waves = 2048
                int v = __hip_atomic_load(&posts[lane + 64 * i],
                                          __ATOMIC_RELAXED, __HIP_MEMORY_SCOPE_AGENT);
                ok &= (v == 1);
            }
        } while (!__all(ok));

        float O = 0.0f;
        for (int cc = 1; cc < NCH; ++cc) {
            float sa = 0.0f, sb = 0.0f;
            for (int j = 4 * lane; j < TSZ; j += 256) {
                v4f a4 = ld_coh4(&ufin[(cc - 1) * TSZ + j]);
                v4f b4 = ld_coh4(&usave[cc * TSZ + j]);
                sa += a4.x + a4.y + a4.z + a4.w;
                sb += b4.x + b4.y + b4.z + b4.w;
            }
            #pragma unroll
            for (int d = 1; d < 64; d <<= 1) {
                sa += __shfl_xor(sa, d, 64);
                sb += __shfl_xor(sb, d, 64);
            }
            O += ld_coh1(&cbuf[cc - 1]) + __logf(sa) - __logf(sb);
        }
        float se = 0.0f;
        for (int j = 4 * lane; j < TSZ; j += 256) {
            const float4 t4 = *(const float4*)(tr + (size_t)END_I * TSZ + j);
            v4f uf = ld_coh4(&ufin[(NCH - 1) * TSZ + j]);
            se += __expf(t4.x) * uf.x + __expf(t4.y) * uf.y +
                  __expf(t4.z) * uf.z + __expf(t4.w) * uf.w;
        }
        #pragma unroll
        for (int d = 1; d < 64; d <<= 1) se += __shfl_xor(se, d, 64);

        float ans = O + ld_coh1(&cbuf[NCH - 1]) + __logf(se);
        if (lane == 0) out[0] = ans;
    }
}

extern "C" void kernel_launch(void* const* d_in, const int* in_sizes, int n_in,
                              void* d_out, int out_size, void* d_ws, size_t ws_size,
                              hipStream_t stream) {
    const float* h  = (const float*)d_in[0];   // [8192, 2048] fp32 emissions
    const float* tr = (const float*)d_in[1];   // [2048, 2048] fp32 transitions
    (void)in_sizes; (void)n_in; (void)out_size; (void)ws_size;
    crf_chain<<<dim3(256), dim3(512), 0, stream>>>(h, tr, (float*)d_out, (float*)d_ws);
}

// Round 8
// 2237.428 us; speedup vs baseline: 695.3810x; 695.3810x over previous
//
#include <hip/hip_runtime.h>

// CRF forward chain on MI355X — linearized: u' = (1/g) diag(exp(h_s)) E u.
// R14: R13's schedule on the PROVEN sc0sc1 sync fabric. R13's sc0-only
// "XCD-local" path was a false coherence assumption (consumer re-served
// stale lines; every poll burned the 16K-try escalation -> 1.5s). Deleted.
// Kept from R13 (vs R11): (1) poll AFTER GEMV — polled value was stored a
// full phase earlier so L3 visibility is pre-paid, first-try hit expected;
// (2) distributed poll — all 8 waves load u redundantly (8x dwordx4), gmax
// needs no cross-wave reduce, each wave packs its 1/8 slice (R11's single
// poller wave serialized 8 loads + reduce + 16 packs while 7 waves idled);
// (3) drain-free s_barrier (lgkmcnt only — no vmcnt(0) store-ack per
// barrier). 2-chain cadence, I$-safe body (2 GEMVs per T).
// NCH=32, CH_LEN=256, BURN=24, TCYC=280, 561 phases. 256 blocks = 1/CU.
//
// ws floats: u_bufs[32][2][2048] @0, usave[32][2048] @131072f,
// ufin[32][2048] @196608f, cbuf[32] @262144f ; posts int[2048] @byte 1048704.

#define TSZ   2048
#define NCH   32
#define NW    8
#define CH_LEN 256
#define BURN  24
#define TCYC  (CH_LEN + BURN)
#define START_I 0
#define END_I   1

typedef float v4f __attribute__((ext_vector_type(4)));
typedef _Float16 h2f __attribute__((ext_vector_type(2)));

__device__ __forceinline__ h2f pk16(float a, float b) {
    return __builtin_bit_cast(h2f, __builtin_amdgcn_cvt_pkrtz(a, b));
}
__device__ __forceinline__ void st_coh(float* p, float v) {
    asm volatile("global_store_dword %0, %1, off sc0 sc1"
                 :: "v"(p), "v"(v) : "memory");
}
__device__ __forceinline__ float ld_coh1(const float* p) {
    float r;
    asm volatile("global_load_dword %0, %1, off sc0 sc1\n\ts_waitcnt vmcnt(0)"
                 : "=&v"(r) : "v"(p) : "memory");
    return r;
}
__device__ __forceinline__ v4f ld_coh4(const float* p) {
    v4f r;
    asm volatile("global_load_dwordx4 %0, %1, off sc0 sc1\n\ts_waitcnt vmcnt(0)"
                 : "=&v"(r) : "v"(p) : "memory");
    return r;
}

__global__ __launch_bounds__(512, 1)
void crf_chain(const float* __restrict__ h, const float* __restrict__ tr,
               float* __restrict__ out, float* __restrict__ ws)
{
    const int tid  = threadIdx.x;
    const int lane = tid & 63;
    const int wv   = tid >> 6;          // 0..7
    const int blk  = blockIdx.x;
    const int g    = blk >> 4;          // group 0..15
    const int b    = blk & 15;          // block within group 0..15
    const int ca   = g;                 // chain X chunk 0..15
    const int cb   = g + 16;            // chain Y chunk 16..31
    const int row_base = b * 128 + wv * 16;

    float* u_bufs = ws;                               // [32][2][2048]
    float* usave  = ws + NCH * 2 * TSZ;               // [32][2048]
    float* ufin   = usave + NCH * TSZ;                // [32][2048]
    float* cbuf   = ufin + NCH * TSZ;                 // [32]
    int*   posts  = (int*)((char*)ws + 1048704);      // [2048]

    __shared__ unsigned long long els64[32][512];     // 4 LDS E-rows/wave, 128KB
    __shared__ unsigned long long uh_sh[2][512];      // packed u per chain, 8KB

    // ---- one-time: register E fragment, 12 rows/wave.
    h2f e2r[12][16];
    #pragma unroll
    for (int r = 0; r < 12; ++r) {
        const float* trow = tr + (size_t)(row_base + r) * TSZ + 4 * lane;
        #pragma unroll
        for (int k = 0; k < 8; ++k) {
            float4 t4 = *(const float4*)(trow + 256 * k);
            e2r[r][2 * k]     = pk16(__expf(t4.x), __expf(t4.y));
            e2r[r][2 * k + 1] = pk16(__expf(t4.z), __expf(t4.w));
        }
    }
    // ---- one-time: LDS E rows 12..15 per wave.
    #pragma unroll
    for (int rr = 0; rr < 4; ++rr) {
        const float* trow = tr + (size_t)(row_base + 12 + rr) * TSZ + 4 * lane;
        #pragma unroll
        for (int k = 0; k < 8; ++k) {
            float4 t4 = *(const float4*)(trow + 256 * k);
            unsigned lo = __builtin_bit_cast(unsigned, pk16(__expf(t4.x), __expf(t4.y)));
            unsigned hi = __builtin_bit_cast(unsigned, pk16(__expf(t4.z), __expf(t4.w)));
            els64[wv * 4 + rr][lane + 64 * k] =
                ((unsigned long long)hi << 32) | (unsigned long long)lo;
        }
    }

    const int q    = ((lane & 1) << 2) | (lane & 2) | ((lane >> 2) & 1);
    const int grow = row_base + q;          // rows grow, grow+8 for lane<8

    // chain schedules
    const int skX = ca * CH_LEN, seX = skX + CH_LEN;
    const int s0X = (ca == 0) ? 0 : (skX - BURN);
    const int TX  = (ca == 0) ? CH_LEN : TCYC;
    const int skY = cb * CH_LEN, seY = skY + CH_LEN;
    const int s0Y = skY - BURN;

    float* ubX = u_bufs + ca * 2 * TSZ;
    float* ubY = u_bufs + cb * 2 * TSZ;

    // ---- init: u^0 parity 0, POSITIVE tag (ws poison 0xAA.. is negative)
    if (tid < 128) {
        int row = b * 128 + tid;
        st_coh(&ubX[row], (ca == 0) ? ((row == START_I) ? 1.0f : 0.0f) : 1.0f);
        st_coh(&ubY[row], 1.0f);
    }

    float ChatX = 0.0f, ChatY = 0.0f;

    // ---- poll full u (8 loads/wave, all waves), gmax in-wave, pack 1/8 slice
    auto POLL_PACK = [&](const float* ubase, int par, int in_neg, int cslot,
                         bool kept, float& ch) {
        const float* pa = ubase + par * TSZ + 4 * lane;   // k=0..3
        const float* pb = pa + 1024;                      // k=4..7
        v4f u0, u1, u2, u3, u4, u5, u6, u7;
        for (;;) {
            asm volatile(
                "global_load_dwordx4 %0, %8, off sc0 sc1\n\t"
                "global_load_dwordx4 %1, %8, off offset:1024 sc0 sc1\n\t"
                "global_load_dwordx4 %2, %8, off offset:2048 sc0 sc1\n\t"
                "global_load_dwordx4 %3, %8, off offset:3072 sc0 sc1\n\t"
                "global_load_dwordx4 %4, %9, off sc0 sc1\n\t"
                "global_load_dwordx4 %5, %9, off offset:1024 sc0 sc1\n\t"
                "global_load_dwordx4 %6, %9, off offset:2048 sc0 sc1\n\t"
                "global_load_dwordx4 %7, %9, off offset:3072 sc0 sc1\n\t"
                "s_waitcnt vmcnt(0)"
                : "=&v"(u0), "=&v"(u1), "=&v"(u2), "=&v"(u3),
                  "=&v"(u4), "=&v"(u5), "=&v"(u6), "=&v"(u7)
                : "v"(pa), "v"(pb)
                : "memory");
            bool fresh;
            if (in_neg) {
                int a = __float_as_int(u0.x) & __float_as_int(u0.y) & __float_as_int(u0.z) & __float_as_int(u0.w);
                a &= __float_as_int(u1.x) & __float_as_int(u1.y) & __float_as_int(u1.z) & __float_as_int(u1.w);
                a &= __float_as_int(u2.x) & __float_as_int(u2.y) & __float_as_int(u2.z) & __float_as_int(u2.w);
                a &= __float_as_int(u3.x) & __float_as_int(u3.y) & __float_as_int(u3.z) & __float_as_int(u3.w);
                a &= __float_as_int(u4.x) & __float_as_int(u4.y) & __float_as_int(u4.z) & __float_as_int(u4.w);
                a &= __float_as_int(u5.x) & __float_as_int(u5.y) & __float_as_int(u5.z) & __float_as_int(u5.w);
                a &= __float_as_int(u6.x) & __float_as_int(u6.y) & __float_as_int(u6.z) & __float_as_int(u6.w);
                a &= __float_as_int(u7.x) & __float_as_int(u7.y) & __float_as_int(u7.z) & __float_as_int(u7.w);
                fresh = (a < 0);
            } else {
                int o = __float_as_int(u0.x) | __float_as_int(u0.y) | __float_as_int(u0.z) | __float_as_int(u0.w);
                o |= __float_as_int(u1.x) | __float_as_int(u1.y) | __float_as_int(u1.z) | __float_as_int(u1.w);
                o |= __float_as_int(u2.x) | __float_as_int(u2.y) | __float_as_int(u2.z) | __float_as_int(u2.w);
                o |= __float_as_int(u3.x) | __float_as_int(u3.y) | __float_as_int(u3.z) | __float_as_int(u3.w);
                o |= __float_as_int(u4.x) | __float_as_int(u4.y) | __float_as_int(u4.z) | __float_as_int(u4.w);
                o |= __float_as_int(u5.x) | __float_as_int(u5.y) | __float_as_int(u5.z) | __float_as_int(u5.w);
                o |= __float_as_int(u6.x) | __float_as_int(u6.y) | __float_as_int(u6.z) | __float_as_int(u6.w);
                o |= __float_as_int(u7.x) | __float_as_int(u7.y) | __float_as_int(u7.z) | __float_as_int(u7.w);
                fresh = (o >= 0);
            }
            if (__all(fresh)) break;
        }
        float m;
        m =          fmaxf(fmaxf(fabsf(u0.x), fabsf(u0.y)), fmaxf(fabsf(u0.z), fabsf(u0.w)));
        m = fmaxf(m, fmaxf(fmaxf(fabsf(u1.x), fabsf(u1.y)), fmaxf(fabsf(u1.z), fabsf(u1.w))));
        m = fmaxf(m, fmaxf(fmaxf(fabsf(u2.x), fabsf(u2.y)), fmaxf(fabsf(u2.z), fabsf(u2.w))));
        m = fmaxf(m, fmaxf(fmaxf(fabsf(u3.x), fabsf(u3.y)), fmaxf(fabsf(u3.z), fabsf(u3.w))));
        m = fmaxf(m, fmaxf(fmaxf(fabsf(u4.x), fabsf(u4.y)), fmaxf(fabsf(u4.z), fabsf(u4.w))));
        m = fmaxf(m, fmaxf(fmaxf(fabsf(u5.x), fabsf(u5.y)), fmaxf(fabsf(u5.z), fabsf(u5.w))));
        m = fmaxf(m, fmaxf(fmaxf(fabsf(u6.x), fabsf(u6.y)), fmaxf(fabsf(u6.z), fabsf(u6.w))));
        m = fmaxf(m, fmaxf(fmaxf(fabsf(u7.x), fabsf(u7.y)), fmaxf(fabsf(u7.z), fabsf(u7.w))));
        #pragma unroll
        for (int d = 1; d < 64; d <<= 1) m = fmaxf(m, __shfl_xor(m, d, 64));

        const float rn = (in_neg ? -1.0f : 1.0f) / m;
        v4f mine = (wv < 4) ? ((wv < 2) ? ((wv == 0) ? u0 : u1)
                                        : ((wv == 2) ? u2 : u3))
                            : ((wv < 6) ? ((wv == 4) ? u4 : u5)
                                        : ((wv == 6) ? u6 : u7));
        unsigned lo = __builtin_bit_cast(unsigned, pk16(mine.x * rn, mine.y * rn));
        unsigned hi = __builtin_bit_cast(unsigned, pk16(mine.z * rn, mine.w * rn));
        uh_sh[cslot][lane + 64 * wv] =
            ((unsigned long long)hi << 32) | (unsigned long long)lo;
        if (kept) ch += __logf(m);
    };

    // ---- GEMV (16 rows/wave: 12 reg + 4 LDS)
    auto GEMV_COMPUTE = [&](const unsigned long long* uh_src, float& outA, float& outB) {
        h2f uh[16];
        #pragma unroll
        for (int k = 0; k < 8; ++k) {
            unsigned long long qw = uh_src[lane + 64 * k];
            uh[2 * k]     = __builtin_bit_cast(h2f, (unsigned)qw);
            uh[2 * k + 1] = __builtin_bit_cast(h2f, (unsigned)(qw >> 32));
        }
        float acc[8];
        #pragma unroll
        for (int r = 0; r < 8; ++r) acc[r] = 0.0f;
        #pragma unroll
        for (int k = 0; k < 16; ++k) {
            #pragma unroll
            for (int r = 0; r < 8; ++r)
                acc[r] = __builtin_amdgcn_fdot2(e2r[r][k], uh[k], acc[r], false);
        }
        #pragma unroll
        for (int r = 0; r < 4; ++r) {
            float send = (lane & 1) ? acc[r] : acc[r + 4];
            float recv = __shfl_xor(send, 1, 64);
            float keep = (lane & 1) ? acc[r + 4] : acc[r];
            acc[r] = keep + recv;
        }
        #pragma unroll
        for (int r = 0; r < 2; ++r) {
            float send = (lane & 2) ? acc[r] : acc[r + 2];
            float recv = __shfl_xor(send, 2, 64);
            float keep = (lane & 2) ? acc[r + 2] : acc[r];
            acc[r] = keep + recv;
        }
        {
            float send = (lane & 4) ? acc[0] : acc[1];
            float recv = __shfl_xor(send, 4, 64);
            float keep = (lane & 4) ? acc[1] : acc[0];
            acc[0] = keep + recv;
        }
        acc[0] += __shfl_xor(acc[0], 8, 64);
        acc[0] += __shfl_xor(acc[0], 16, 64);
        acc[0] += __shfl_xor(acc[0], 32, 64);
        outA = acc[0];

        #pragma unroll
        for (int r = 0; r < 8; ++r) acc[r] = 0.0f;
        #pragma unroll
        for (int k = 0; k < 8; ++k) {
            unsigned long long q0 = els64[wv * 4 + 0][lane + 64 * k];
            unsigned long long q1 = els64[wv * 4 + 1][lane + 64 * k];
            unsigned long long q2 = els64[wv * 4 + 2][lane + 64 * k];
            unsigned long long q3 = els64[wv * 4 + 3][lane + 64 * k];
            #pragma unroll
            for (int r = 0; r < 4; ++r) {
                acc[r] = __builtin_amdgcn_fdot2(e2r[8 + r][2 * k],     uh[2 * k],     acc[r], false);
                acc[r] = __builtin_amdgcn_fdot2(e2r[8 + r][2 * k + 1], uh[2 * k + 1], acc[r], false);
            }
            acc[4] = __builtin_amdgcn_fdot2(__builtin_bit_cast(h2f, (unsigned)q0),         uh[2 * k],     acc[4], false);
            acc[4] = __builtin_amdgcn_fdot2(__builtin_bit_cast(h2f, (unsigned)(q0 >> 32)), uh[2 * k + 1], acc[4], false);
            acc[5] = __builtin_amdgcn_fdot2(__builtin_bit_cast(h2f, (unsigned)q1),         uh[2 * k],     acc[5], false);
            acc[5] = __builtin_amdgcn_fdot2(__builtin_bit_cast(h2f, (unsigned)(q1 >> 32)), uh[2 * k + 1], acc[5], false);
            acc[6] = __builtin_amdgcn_fdot2(__builtin_bit_cast(h2f, (unsigned)q2),         uh[2 * k],     acc[6], false);
            acc[6] = __builtin_amdgcn_fdot2(__builtin_bit_cast(h2f, (unsigned)(q2 >> 32)), uh[2 * k + 1], acc[6], false);
            acc[7] = __builtin_amdgcn_fdot2(__builtin_bit_cast(h2f, (unsigned)q3),         uh[2 * k],     acc[7], false);
            acc[7] = __builtin_amdgcn_fdot2(__builtin_bit_cast(h2f, (unsigned)(q3 >> 32)), uh[2 * k + 1], acc[7], false);
        }
        #pragma unroll
        for (int r = 0; r < 4; ++r) {
            float send = (lane & 1) ? acc[r] : acc[r + 4];
            float recv = __shfl_xor(send, 1, 64);
            float keep = (lane & 1) ? acc[r + 4] : acc[r];
            acc[r] = keep + recv;
        }
        #pragma unroll
        for (int r = 0; r < 2; ++r) {
            float send = (lane & 2) ? acc[r] : acc[r + 2];
            float recv = __shfl_xor(send, 2, 64);
            float keep = (lane & 2) ? acc[r + 2] : acc[r];
            acc[r] = keep + recv;
        }
        {
            float send = (lane & 4) ? acc[0] : acc[1];
            float recv = __shfl_xor(send, 4, 64);
            float keep = (lane & 4) ? acc[1] : acc[0];
            acc[0] = keep + recv;
        }
        acc[0] += __shfl_xor(acc[0], 8, 64);
        acc[0] += __shfl_xor(acc[0], 16, 64);
        acc[0] += __shfl_xor(acc[0], 32, 64);
        outB = acc[0];
    };

    // drain-free barrier: LDS consistency only; stores stay in flight.
    auto BAR = [&]() {
        __builtin_amdgcn_sched_barrier(0);
        asm volatile("s_waitcnt lgkmcnt(0)" ::: "memory");
        __builtin_amdgcn_s_barrier();
        __builtin_amdgcn_sched_barrier(0);
    };

    // ---- prologue: pack chain X u_0 into uh_sh[0]
    POLL_PACK(ubX, 0, 0, 0, (s0X + 1) > skX, ChatX);
    BAR();   // els64 + uh_sh[0] ready

    // ================= main loop: 2 phases per T ============================
    for (int T = 0; T < TCYC; ++T) {
        const int outp = (T + 1) & 1, outn = ((T + 1) >> 1) & 1;

        // ---- even phase: compute X@T; then poll+pack Y u_T (stored last iter)
        {
            const int sX = s0X + T;
            const bool doX = (T < TX);
            float h0 = 0.0f, h1 = 0.0f;
            if (doX && lane < 8) {
                h0 = h[(size_t)sX * TSZ + grow];
                h1 = h[(size_t)sX * TSZ + grow + 8];
            }
            if (doX) {
                float rA, rB;
                GEMV_COMPUTE(&uh_sh[0][0], rA, rB);
                if (lane < 8) {
                    float utA = rA * __expf(h0);
                    float utB = rB * __expf(h1);
                    float* uo = ubX + outp * TSZ;
                    st_coh(&uo[grow],     outn ? -utA : utA);
                    st_coh(&uo[grow + 8], outn ? -utB : utB);
                    if (ca > 0 && sX + 1 == skX) {
                        st_coh(&usave[ca * TSZ + grow],     utA);
                        st_coh(&usave[ca * TSZ + grow + 8], utB);
                    }
                    if (sX + 1 == seX) {
                        st_coh(&ufin[ca * TSZ + grow],     utA);
                        st_coh(&ufin[ca * TSZ + grow + 8], utB);
                    }
                }
            }
            // poll Y's u_T (v=T): parity T&1, tag (T>>1)&1
            POLL_PACK(ubY, T & 1, (T >> 1) & 1, 1, (s0Y + T + 1) > skY, ChatY);
            BAR();
        }

        // ---- odd phase: compute Y@T; then poll+pack X u_{T+1} (stored above)
        {
            const int sY = s0Y + T;
            float h0 = 0.0f, h1 = 0.0f;
            if (lane < 8) {
                h0 = h[(size_t)sY * TSZ + grow];
                h1 = h[(size_t)sY * TSZ + grow + 8];
            }
            {
                float rA, rB;
                GEMV_COMPUTE(&uh_sh[1][0], rA, rB);
                if (lane < 8) {
                    float utA = rA * __expf(h0);
                    float utB = rB * __expf(h1);
                    float* uo = ubY + outp * TSZ;
                    st_coh(&uo[grow],     outn ? -utA : utA);
                    st_coh(&uo[grow + 8], outn ? -utB : utB);
                    if (sY + 1 == skY) {
                        st_coh(&usave[cb * TSZ + grow],     utA);
                        st_coh(&usave[cb * TSZ + grow + 8], utB);
                    }
                    if (sY + 1 == seY) {
                        st_coh(&ufin[cb * TSZ + grow],     utA);
                        st_coh(&ufin[cb * TSZ + grow + 8], utB);
                    }
                }
            }
            // poll X's u_{T+1} if X still running
            const int v = T + 1;
            if (v < TX)
                POLL_PACK(ubX, v & 1, (v >> 1) & 1, 0, (s0X + v + 1) > skX, ChatX);
            BAR();
        }
    }

    // ---- completion: store Chats, ack all stores, per-wave post
    if (b == 0 && wv == 0 && lane == 0) {
        st_coh(&cbuf[ca], ChatX);
        st_coh(&cbuf[cb], ChatY);
    }
    asm volatile("s_waitcnt vmcnt(0)" ::: "memory");
    if (lane == 0)
        __hip_atomic_store(&posts[blk * NW + wv], 1,
                           __ATOMIC_RELAXED, __HIP_MEMORY_SCOPE_AGENT);

    // ---- finisher: block 0 / wave 0 stitches 32 chunks
    if (blk == 0 && wv == 0) {
        int ok;
        do {
            __builtin_amdgcn_s_sleep(1);
            ok = 1;
            #pragma unroll
            for (int i = 0; i < 32; ++i) {     // 256 blocks x 8 waves = 2048
                int v = __hip_atomic_load(&posts[lane + 64 * i],
                                          __ATOMIC_RELAXED, __HIP_MEMORY_SCOPE_AGENT);
                ok &= (v == 1);
            }
        } while (!__all(ok));

        float O = 0.0f;
        for (int cc = 1; cc < NCH; ++cc) {
            float sa = 0.0f, sb = 0.0f;
            for (int j = 4 * lane; j < TSZ; j += 256) {
                v4f a4 = ld_coh4(&ufin[(cc - 1) * TSZ + j]);
                v4f b4 = ld_coh4(&usave[cc * TSZ + j]);
                sa += a4.x + a4.y + a4.z + a4.w;
                sb += b4.x + b4.y + b4.z + b4.w;
            }
            #pragma unroll
            for (int d = 1; d < 64; d <<= 1) {
                sa += __shfl_xor(sa, d, 64);
                sb += __shfl_xor(sb, d, 64);
            }
            O += ld_coh1(&cbuf[cc - 1]) + __logf(sa) - __logf(sb);
        }
        float se = 0.0f;
        for (int j = 4 * lane; j < TSZ; j += 256) {
            const float4 t4 = *(const float4*)(tr + (size_t)END_I * TSZ + j);
            v4f uf = ld_coh4(&ufin[(NCH - 1) * TSZ + j]);
            se += __expf(t4.x) * uf.x + __expf(t4.y) * uf.y +
                  __expf(t4.z) * uf.z + __expf(t4.w) * uf.w;
        }
        #pragma unroll
        for (int d = 1; d < 64; d <<= 1) se += __shfl_xor(se, d, 64);

        float ans = O + ld_coh1(&cbuf[NCH - 1]) + __logf(se);
        if (lane == 0) out[0] = ans;
    }
}

extern "C" void kernel_launch(void* const* d_in, const int* in_sizes, int n_in,
                              void* d_out, int out_size, void* d_ws, size_t ws_size,
                              hipStream_t stream) {
    const float* h  = (const float*)d_in[0];   // [8192, 2048] fp32 emissions
    const float* tr = (const float*)d_in[1];   // [2048, 2048] fp32 transitions
    (void)in_sizes; (void)n_in; (void)out_size; (void)ws_size;
    crf_chain<<<dim3(256), dim3(512), 0, stream>>>(h, tr, (float*)d_out, (float*)d_ws);
}